// Round 7
// baseline (477.680 us; speedup 1.0000x reference)
//
#include <hip/hip_runtime.h>
#include <hip/hip_bf16.h>

// Problem constants
constexpr int kB  = 4;
constexpr int kS  = 1024;
constexpr int kD  = 2048;
constexpr int kH  = 32;
constexpr int kKV = 8;
constexpr int kHD = 64;
constexpr int kM  = kB * kS;    // 4096
constexpr int kNT = kS / 64;    // 16 kv tiles

constexpr float kNegBig = -30000.0f;   // finite sentinel: no inf/overflow paths
constexpr float kC = 0.125f * 1.44269504f;  // 1/sqrt(HD) folded into exp2
constexpr float kDeferThr = 40.0f;     // defer-max raw threshold: P <= 2^(40*kC) ~ 147

typedef __attribute__((ext_vector_type(8))) short short8;   // 8 bf16 (4 VGPRs)
typedef __attribute__((ext_vector_type(4))) float floatx4;  // MFMA C/D

static __device__ __forceinline__ short f2bf(float f) {
    unsigned int u = __builtin_bit_cast(unsigned int, f);
    unsigned int lsb = (u >> 16) & 1u;
    u += 0x7fffu + lsb;                       // round-to-nearest-even
    return (short)(u >> 16);
}
// Cheap pack for P >= 0: round-half-up (bias ~2^-9 relative, harmless).
static __device__ __forceinline__ short f2bf_fast(float f) {
    unsigned int u = __builtin_bit_cast(unsigned int, f);
    return (short)((u + 0x8000u) >> 16);
}

// Async global->LDS, 16 B per lane. LDS dest is wave-uniform base + lane*16.
static __device__ __forceinline__ void load_lds16(const short* g, short* l) {
    __builtin_amdgcn_global_load_lds(
        (const __attribute__((address_space(1))) unsigned int*)g,
        (__attribute__((address_space(3))) unsigned int*)l, 16, 0, 0);
}

// fp32 -> bf16, vectorized x4. n4 = element_count/4.
__global__ void cast_f2b(const float* __restrict__ in, short* __restrict__ outp, int n4) {
    int gid = blockIdx.x * blockDim.x + threadIdx.x;
    if (gid >= n4) return;
    float4 v = ((const float4*)in)[gid];
    short4 o;
    o.x = f2bf(v.x); o.y = f2bf(v.y); o.z = f2bf(v.z); o.w = f2bf(v.w);
    ((short4*)outp)[gid] = o;
}

// Fused 4-source cast (x, wq, wk, wv) — one launch instead of four.
__global__ void cast4_f2b(const float* __restrict__ a, const float* __restrict__ b,
                          const float* __restrict__ c, const float* __restrict__ d,
                          short* __restrict__ oa, short* __restrict__ ob,
                          short* __restrict__ oc, short* __restrict__ od,
                          int na4, int nb4, int nc4, int nd4) {
    int gid = blockIdx.x * blockDim.x + threadIdx.x;
    const float* src; short* dst; int idx;
    if (gid < na4)                    { src = a; dst = oa; idx = gid; }
    else if (gid < na4 + nb4)         { src = b; dst = ob; idx = gid - na4; }
    else if (gid < na4 + nb4 + nc4)   { src = c; dst = oc; idx = gid - na4 - nb4; }
    else if (gid < na4+nb4+nc4+nd4)   { src = d; dst = od; idx = gid - na4 - nb4 - nc4; }
    else return;
    float4 v = ((const float4*)src)[idx];
    short4 o;
    o.x = f2bf(v.x); o.y = f2bf(v.y); o.z = f2bf(v.z); o.w = f2bf(v.w);
    ((short4*)dst)[idx] = o;
}

// C[M,N] = A[M,K] * B[N,K]^T, bf16 in, fp32 acc.
// m97 structure: 128x128 tile, BK=32, global_load_lds width=16 staging,
// 2-barrier K-loop, ds_read_b128 fragments. Block = 4 waves in 2x2.
// XCD-aware bijective blockIdx swizzle (T1); requires nwg % 8 == 0 (guarded).
// ROPE = 0: plain GEMM, OT out (fp32 for out-proj).
// ROPE = 3: fused QKV projection, N = 3072 columns:
//   cols [0,2048): Q + RoPE (head = col>>6)        -> C   [row*2048 + col]  bf16
//   cols [2048,2560): K + RoPE (head = (col-2048)>>6) -> Kout[row*1024 + col-2048]
//   cols [2560,3072): V, stored TRANSPOSED          -> Vt  [(col-2560)*M + row]
//   B rows < 2048 come from Bm (wq), rows >= 2048 from B2 (wk|wv); the split
//   at 2048 is a multiple of the 128-tile so each block reads one source.
// RoPE on fp32 acc: pair (2i,2i+1) is in adjacent lanes (l16 even/odd),
// exchanged with shfl_xor(v,1). Angle indexed by HEAD (reference quirk).
template <typename OT, int ROPE>
__global__ __launch_bounds__(256) void gemm_bt_lds(const short* __restrict__ A,
                                                   const short* __restrict__ Bm,
                                                   OT* __restrict__ C,
                                                   int M, int N, int K,
                                                   const float* __restrict__ cosb,
                                                   const float* __restrict__ sinb,
                                                   short* __restrict__ Vt,
                                                   const short* __restrict__ B2,
                                                   short* __restrict__ Kout) {
    __shared__ short As[128 * 32];
    __shared__ short Bs[128 * 32];

    int tid  = threadIdx.x;
    int wave = tid >> 6, lane = tid & 63;
    int quad = lane >> 4, l16 = lane & 15;
    int wm = wave >> 1, wn = wave & 1;

    // XCD swizzle (8 XCDs round-robin on default dispatch)
    int nwg  = gridDim.x * gridDim.y;
    int orig = blockIdx.y * gridDim.x + blockIdx.x;
    int wg   = orig;
    if ((nwg & 7) == 0) {
        int cpx = nwg >> 3;
        wg = (orig & 7) * cpx + (orig >> 3);
    }
    int bx = wg % gridDim.x, by = wg / gridDim.x;
    int m0 = by * 128, n0 = bx * 128;

    // B source for this block's 128 columns (row-region uniform per block).
    const short* Bblk;
    if constexpr (ROPE == 3)
        Bblk = (n0 < 2048) ? Bm + (long)n0 * K : B2 + (long)(n0 - 2048) * K;
    else
        Bblk = Bm + (long)n0 * K;

    floatx4 acc[4][4];
    for (int i = 0; i < 4; i++)
        for (int j = 0; j < 4; j++) acc[i][j] = (floatx4){0.f, 0.f, 0.f, 0.f};

    int srow = lane >> 2;           // 0..15
    int skc  = (lane & 3) * 8;      // 0,8,16,24

    for (int k0 = 0; k0 < K; k0 += 32) {
        __syncthreads();
        for (int i = 0; i < 2; i++) {
            int r16 = wave * 32 + i * 16;
            load_lds16(A + (long)(m0 + r16 + srow) * K + k0 + skc, &As[r16 * 32]);
            load_lds16(Bblk + (long)(r16 + srow) * K + k0 + skc, &Bs[r16 * 32]);
        }
        __syncthreads();

        short8 af[4], bfr[4];
        for (int i = 0; i < 4; i++)
            af[i] = *(const short8*)&As[(wm * 64 + i * 16 + l16) * 32 + quad * 8];
        for (int j = 0; j < 4; j++)
            bfr[j] = *(const short8*)&Bs[(wn * 64 + j * 16 + l16) * 32 + quad * 8];
        for (int i = 0; i < 4; i++)
            for (int j = 0; j < 4; j++)
                acc[i][j] = __builtin_amdgcn_mfma_f32_16x16x32_bf16(
                    af[i], bfr[j], acc[i][j], 0, 0, 0);
    }

    if constexpr (ROPE == 3) {
        for (int j = 0; j < 4; j++) {
            int col = n0 + wn * 64 + j * 16 + l16;
            if (col >= 2560) {            // V: transposed store Vt[d][row]
                int cv = col - 2560;
                for (int i = 0; i < 4; i++) {
                    int row0 = m0 + wm * 64 + i * 16 + quad * 4;
                    short4 o;
                    o.x = f2bf(acc[i][j][0]);
                    o.y = f2bf(acc[i][j][1]);
                    o.z = f2bf(acc[i][j][2]);
                    o.w = f2bf(acc[i][j][3]);
                    *(short4*)&Vt[(long)cv * M + row0] = o;
                }
            } else {                      // Q or K: RoPE'd row-major store
                bool isK = col >= 2048;
                int hh = isK ? ((col - 2048) >> 6) : (col >> 6);
                int ii = (col & 63) >> 1;
                float c = cosb[hh * 32 + ii];
                float s = sinb[hh * 32 + ii];
                for (int i = 0; i < 4; i++) {
                    for (int r = 0; r < 4; r++) {
                        int row = m0 + wm * 64 + i * 16 + quad * 4 + r;
                        float v = acc[i][j][r];
                        float p = __shfl_xor(v, 1);   // pair partner
                        v = (col & 1) ? (p * s + v * c)    // o1 = t0*s + t1*c
                                      : (v * c - p * s);   // o0 = t0*c - t1*s
                        if (isK)
                            Kout[(long)row * 1024 + (col - 2048)] = f2bf(v);
                        else
                            ((short*)C)[(long)row * 2048 + col] = f2bf(v);
                    }
                }
            }
        }
    } else {
        for (int j = 0; j < 4; j++) {
            int col = n0 + wn * 64 + j * 16 + l16;
            for (int i = 0; i < 4; i++)
                for (int r = 0; r < 4; r++) {
                    int row = m0 + wm * 64 + i * 16 + quad * 4 + r;
                    float v = acc[i][j][r];
                    if constexpr (sizeof(OT) == 2)
                        C[(long)row * N + col] = f2bf(v);
                    else
                        C[(long)row * N + col] = v;
                }
        }
    }
}

// Fused causal GQA flash attention — Round-13: residency fix.
// Round-6 showed VGPR 152 -> 3 waves/SIMD cap while the grid needs 4
// blocks/CU, forcing a second shift at 1/3 residency (occ 11%, 66% idle).
// Fix: single K register buffer rotated in-place (K(t+1) loaded right after
// QK^T(t) consumed kf) + __launch_bounds__(256,4) to force VGPR <= 128 ->
// exactly 4 blocks/CU, one shift. V issued at step start, consumed after
// softmax (~500 cyc cover). Uniform pairing retained: block pb owns q-tiles
// {15-pb, pb} = 17 kv-iters for every block. Barrier-free (pT wave-private).
// Grid: (S/128, H, B); block 256 = 4 waves.
__global__ __launch_bounds__(256, 4) void attn_kernel(const short* __restrict__ xq,
                                                      const short* __restrict__ xk,
                                                      const short* __restrict__ vt,
                                                      short* __restrict__ out,
                                                      int kvstride) {
    __shared__ short pT[4][16][72];   // per-wave P tile [row][key] (+pad)

    int pb = blockIdx.x;              // 0..7: handles q-tiles {15-pb, pb}
    int h = blockIdx.y, b = blockIdx.z;
    int kvh = h >> 2;                 // GQA repeat_interleave: head h <- kv h/4
    int tid = threadIdx.x, wave = tid >> 6, lane = tid & 63;
    int quad = lane >> 4, l16 = lane & 15;

    const short* kbase0 = xk + (long)b * kS * kvstride + kvh * kHD;
    // Vt layout: [kvh*64 + d][b*kS + s], row stride kM.
    const short* vbase = vt + (long)kvh * kHD * kM + (long)b * kS;

    // all-ones bf16 B-fragment: mfma(P, ones) puts row-sum(P) in every column
    short8 ones;
    for (int i = 0; i < 8; i++) ones[i] = (short)0x3F80;

    auto loadK = [&](short8 (&kf)[4][2], int kt) {
        const short* kbase = kbase0 + (long)kt * 64 * kvstride;
        for (int kb = 0; kb < 4; kb++) {
            const short* kp = kbase + (long)(kb * 16 + l16) * kvstride + quad * 8;
            kf[kb][0] = *(const short8*)kp;
            kf[kb][1] = *(const short8*)(kp + 32);
        }
    };

    for (int qi = 0; qi < 2; qi++) {
        int qb = (qi == 0) ? (kNT - 1 - pb) : pb;   // heavy tile first
        int nt = qb + 1;
        int wr0  = qb * 64 + wave * 16;
        int qrow = wr0 + l16;
        int crow = wr0 + quad * 4;

        const short* qp = xq + (((long)b * kS + qrow) * kH + h) * kHD + quad * 8;
        short8 qf0 = *(const short8*)(qp);
        short8 qf1 = *(const short8*)(qp + 32);

        float m_run[4];
        floatx4 acc_l = (floatx4){0.f, 0.f, 0.f, 0.f};
        floatx4 acc_o[4];
        for (int r = 0; r < 4; r++) m_run[r] = kNegBig;
        for (int nb = 0; nb < 4; nb++) acc_o[nb] = (floatx4){0.f, 0.f, 0.f, 0.f};

        short8 kf[4][2];
        loadK(kf, 0);

        for (int kt = 0; kt < nt; kt++) {
            // V fragments for THIS tile: issue first (longest latency cover).
            // vf[nb][ks][j] = V[key=kt*64+ks*32+quad*8+j][d=nb*16+l16]
            short8 vf[4][2];
            for (int nb = 0; nb < 4; nb++) {
                const short* vp = vbase + (long)(nb * 16 + l16) * kM + kt * 64 + quad * 8;
                vf[nb][0] = *(const short8*)(vp);
                vf[nb][1] = *(const short8*)(vp + 32);
            }

            // Scores (raw): Q(16xHD) x K^T(HDx64), 4 key-blocks.
            floatx4 accs[4];
            __builtin_amdgcn_s_setprio(1);
            for (int kb = 0; kb < 4; kb++) {
                accs[kb] = (floatx4){0.f, 0.f, 0.f, 0.f};
                accs[kb] = __builtin_amdgcn_mfma_f32_16x16x32_bf16(qf0, kf[kb][0], accs[kb], 0, 0, 0);
                accs[kb] = __builtin_amdgcn_mfma_f32_16x16x32_bf16(qf1, kf[kb][1], accs[kb], 0, 0, 0);
            }
            __builtin_amdgcn_s_setprio(0);

            // Rotate K buffer in place: next tile's K, issued right after the
            // QK MFMAs consumed kf; covered by softmax+pT+PV (~700 cyc).
            if (kt + 1 < nt) loadK(kf, kt + 1);

            if (kt == nt - 1) {  // causal mask: only the diagonal tile
                for (int kb = 0; kb < 4; kb++)
                    for (int r = 0; r < 4; r++) {
                        int kj = kt * 64 + kb * 16 + l16;
                        if (kj > crow + r) accs[kb][r] = kNegBig;
                    }
            }

            // Online softmax with defer-max (16-lane exact max per row).
            float mx[4];
            for (int r = 0; r < 4; r++) {
                float m1 = fmaxf(fmaxf(accs[0][r], accs[1][r]),
                                 fmaxf(accs[2][r], accs[3][r]));
                for (int off = 1; off < 16; off <<= 1) m1 = fmaxf(m1, __shfl_xor(m1, off));
                mx[r] = m1;
            }
            bool small = (mx[0] - m_run[0] <= kDeferThr) && (mx[1] - m_run[1] <= kDeferThr) &&
                         (mx[2] - m_run[2] <= kDeferThr) && (mx[3] - m_run[3] <= kDeferThr);
            if (!__all(small)) {
                for (int r = 0; r < 4; r++) {
                    float mnew = fmaxf(m_run[r], mx[r]);
                    float alpha = exp2f((m_run[r] - mnew) * kC);
                    m_run[r] = mnew;
                    acc_l[r] *= alpha;
                    for (int nb = 0; nb < 4; nb++) acc_o[nb][r] *= alpha;
                }
            }

            // P = 2^(s*kC - m*kC); P <= 2^(kDeferThr*kC) ~ 147 (bf16-safe).
            for (int r = 0; r < 4; r++) {
                float mk = m_run[r] * kC;
                for (int kb = 0; kb < 4; kb++)
                    accs[kb][r] = exp2f(fmaf(accs[kb][r], kC, -mk));
            }

            // P -> LDS (C-layout to A-layout transpose, wave-private).
            for (int r = 0; r < 4; r++)
                for (int kb = 0; kb < 4; kb++)
                    pT[wave][quad * 4 + r][kb * 16 + l16] = f2bf_fast(accs[kb][r]);

            // PV + row-sum: P(16x64) x [V(64xHD) | ones]
            short8 pf0 = *(const short8*)&pT[wave][l16][quad * 8];
            short8 pf1 = *(const short8*)&pT[wave][l16][32 + quad * 8];
            __builtin_amdgcn_s_setprio(1);
            acc_l = __builtin_amdgcn_mfma_f32_16x16x32_bf16(pf0, ones, acc_l, 0, 0, 0);
            acc_l = __builtin_amdgcn_mfma_f32_16x16x32_bf16(pf1, ones, acc_l, 0, 0, 0);
            for (int nb = 0; nb < 4; nb++) {
                acc_o[nb] = __builtin_amdgcn_mfma_f32_16x16x32_bf16(pf0, vf[nb][0], acc_o[nb], 0, 0, 0);
                acc_o[nb] = __builtin_amdgcn_mfma_f32_16x16x32_bf16(pf1, vf[nb][1], acc_o[nb], 0, 0, 0);
            }
            __builtin_amdgcn_s_setprio(0);
        }

        // Epilogue: normalize and store (B,S,H,HD) bf16.
        for (int r = 0; r < 4; r++) {
            float inv = 1.0f / fmaxf(acc_l[r], 1e-20f);
            int row = crow + r;
            for (int nb = 0; nb < 4; nb++)
                out[(((long)b * kS + row) * kH + h) * kHD + nb * 16 + l16] =
                    f2bf(acc_o[nb][r] * inv);
        }
    }
}

extern "C" void kernel_launch(void* const* d_in, const int* in_sizes, int n_in,
                              void* d_out, int out_size, void* d_ws, size_t ws_size,
                              hipStream_t stream) {
    // setup_inputs order: x, freqs_cos, freqs_sin, mask, wq, wk, wv, wo
    const float* x  = (const float*)d_in[0];
    const float* fc = (const float*)d_in[1];
    const float* fs = (const float*)d_in[2];
    // d_in[3] = mask: structurally causal, implemented structurally.
    const float* wq = (const float*)d_in[4];
    const float* wk = (const float*)d_in[5];
    const float* wv = (const float*)d_in[6];
    const float* wo = (const float*)d_in[7];

    const int M = kM;                     // 4096
    const long MB = 1l << 20;

    // ws (peak 24 MiB):                   d_out (32 MiB):
    //   [ 0,16) xb   — dead after QKV GEMM  [ 0,16) xq bf16 (M x 2048)
    //   [16,24) wqb  — dead after QKV GEMM  [16,24) xkv bf16 (M x 1024, K in 0..511)
    //   [ 0,16) ao   (over xb)              [24,28) vt bf16 (512 x M, transposed V)
    //   [16,24) wob  (over wqb)             [28,32) wkvb bf16 (1024 x 2048: wk|wv)
    //                                        final: 32 MiB fp32 out (last GEMM)
    char* ws = (char*)d_ws;
    short* xb   = (short*)(ws);
    short* wqb  = (short*)(ws + 16 * MB);
    short* ao   = (short*)(ws);
    short* wob  = (short*)(ws + 16 * MB);
    char*  dob  = (char*)d_out;
    short* xq   = (short*)(dob);
    short* xkv  = (short*)(dob + 16 * MB);
    short* vt   = (short*)(dob + 24 * MB);
    short* wkvb = (short*)(dob + 28 * MB);

    const int nX  = M * kD;         // 8388608
    const int nWq = kD * kD;        // 4194304
    const int nWk = kKV * kHD * kD; // 1048576

    // One fused cast: x -> xb, wq -> wqb, wk -> wkvb[0,1M), wv -> wkvb[1M,2M)
    int total4 = (nX + nWq + 2 * nWk) / 4;
    cast4_f2b<<<(total4 + 255) / 256, 256, 0, stream>>>(
        x, wq, wk, wv, xb, wqb, wkvb, wkvb + nWk,
        nX / 4, nWq / 4, nWk / 4, nWk / 4);

    // Fused QKV projection (N = 3072): Q+RoPE -> xq, K+RoPE -> xkv, V^T -> vt.
    gemm_bt_lds<short, 3><<<dim3(3072 / 128, M / 128), 256, 0, stream>>>(
        xb, wqb, xq, M, 3072, kD, fc, fs, vt, wkvb, xkv);

    attn_kernel<<<dim3(kS / 128, kH, kB), 256, 0, stream>>>(
        xq, xkv, vt, ao, 1024);

    cast_f2b<<<(nWq / 4 + 255) / 256, 256, 0, stream>>>(wo, wob, nWq / 4);
    gemm_bt_lds<float, 0><<<dim3(kD / 128, M / 128), 256, 0, stream>>>(
        ao, wob, (float*)d_out, M, kD, kD, nullptr, nullptr, nullptr, nullptr, nullptr);
}

// Round 8
// 417.783 us; speedup vs baseline: 1.1434x; 1.1434x over previous
//
#include <hip/hip_runtime.h>
#include <hip/hip_bf16.h>

// Problem constants
constexpr int kB  = 4;
constexpr int kS  = 1024;
constexpr int kD  = 2048;
constexpr int kH  = 32;
constexpr int kKV = 8;
constexpr int kHD = 64;
constexpr int kM  = kB * kS;    // 4096
constexpr int kNT = kS / 64;    // 16 kv tiles

constexpr float kNegBig = -30000.0f;   // finite sentinel: no inf/overflow paths
constexpr float kC = 0.125f * 1.44269504f;  // 1/sqrt(HD) folded into exp2
constexpr float kDeferThr = 40.0f;     // defer-max raw threshold: P <= 2^(40*kC) ~ 147

typedef __attribute__((ext_vector_type(8))) short short8;   // 8 bf16 (4 VGPRs)
typedef __attribute__((ext_vector_type(4))) float floatx4;  // MFMA C/D

static __device__ __forceinline__ short f2bf(float f) {
    unsigned int u = __builtin_bit_cast(unsigned int, f);
    unsigned int lsb = (u >> 16) & 1u;
    u += 0x7fffu + lsb;                       // round-to-nearest-even
    return (short)(u >> 16);
}
// Cheap pack for P >= 0: round-half-up (bias ~2^-9 relative, harmless).
static __device__ __forceinline__ short f2bf_fast(float f) {
    unsigned int u = __builtin_bit_cast(unsigned int, f);
    return (short)((u + 0x8000u) >> 16);
}

// Async global->LDS, 16 B per lane. LDS dest is wave-uniform base + lane*16.
static __device__ __forceinline__ void load_lds16(const short* g, short* l) {
    __builtin_amdgcn_global_load_lds(
        (const __attribute__((address_space(1))) unsigned int*)g,
        (__attribute__((address_space(3))) unsigned int*)l, 16, 0, 0);
}

// fp32 -> bf16, vectorized x4. n4 = element_count/4.
__global__ void cast_f2b(const float* __restrict__ in, short* __restrict__ outp, int n4) {
    int gid = blockIdx.x * blockDim.x + threadIdx.x;
    if (gid >= n4) return;
    float4 v = ((const float4*)in)[gid];
    short4 o;
    o.x = f2bf(v.x); o.y = f2bf(v.y); o.z = f2bf(v.z); o.w = f2bf(v.w);
    ((short4*)outp)[gid] = o;
}

// Fused 4-source cast (x, wq, wk, wv) — one launch instead of four.
__global__ void cast4_f2b(const float* __restrict__ a, const float* __restrict__ b,
                          const float* __restrict__ c, const float* __restrict__ d,
                          short* __restrict__ oa, short* __restrict__ ob,
                          short* __restrict__ oc, short* __restrict__ od,
                          int na4, int nb4, int nc4, int nd4) {
    int gid = blockIdx.x * blockDim.x + threadIdx.x;
    const float* src; short* dst; int idx;
    if (gid < na4)                    { src = a; dst = oa; idx = gid; }
    else if (gid < na4 + nb4)         { src = b; dst = ob; idx = gid - na4; }
    else if (gid < na4 + nb4 + nc4)   { src = c; dst = oc; idx = gid - na4 - nb4; }
    else if (gid < na4+nb4+nc4+nd4)   { src = d; dst = od; idx = gid - na4 - nb4 - nc4; }
    else return;
    float4 v = ((const float4*)src)[idx];
    short4 o;
    o.x = f2bf(v.x); o.y = f2bf(v.y); o.z = f2bf(v.z); o.w = f2bf(v.w);
    ((short4*)dst)[idx] = o;
}

// C[M,N] = A[M,K] * B[N,K]^T, bf16 in, fp32 acc.
// m97 structure: 128x128 tile, BK=32, global_load_lds width=16 staging,
// 2-barrier K-loop, ds_read_b128 fragments. Block = 4 waves in 2x2.
// XCD-aware bijective blockIdx swizzle (T1); requires nwg % 8 == 0 (guarded).
// ROPE = 0: plain GEMM, OT out (fp32 for out-proj).
// ROPE = 3: fused QKV projection, N = 3072 columns:
//   cols [0,2048): Q + RoPE (head = col>>6)        -> C   [row*2048 + col]  bf16
//   cols [2048,2560): K + RoPE (head = (col-2048)>>6) -> Kout[row*1024 + col-2048]
//   cols [2560,3072): V, stored TRANSPOSED          -> Vt  [(col-2560)*M + row]
//   B rows < 2048 come from Bm (wq), rows >= 2048 from B2 (wk|wv); the split
//   at 2048 is a multiple of the 128-tile so each block reads one source.
// RoPE on fp32 acc: pair (2i,2i+1) is in adjacent lanes (l16 even/odd),
// exchanged with shfl_xor(v,1). Angle indexed by HEAD (reference quirk).
template <typename OT, int ROPE>
__global__ __launch_bounds__(256) void gemm_bt_lds(const short* __restrict__ A,
                                                   const short* __restrict__ Bm,
                                                   OT* __restrict__ C,
                                                   int M, int N, int K,
                                                   const float* __restrict__ cosb,
                                                   const float* __restrict__ sinb,
                                                   short* __restrict__ Vt,
                                                   const short* __restrict__ B2,
                                                   short* __restrict__ Kout) {
    __shared__ short As[128 * 32];
    __shared__ short Bs[128 * 32];

    int tid  = threadIdx.x;
    int wave = tid >> 6, lane = tid & 63;
    int quad = lane >> 4, l16 = lane & 15;
    int wm = wave >> 1, wn = wave & 1;

    // XCD swizzle (8 XCDs round-robin on default dispatch)
    int nwg  = gridDim.x * gridDim.y;
    int orig = blockIdx.y * gridDim.x + blockIdx.x;
    int wg   = orig;
    if ((nwg & 7) == 0) {
        int cpx = nwg >> 3;
        wg = (orig & 7) * cpx + (orig >> 3);
    }
    int bx = wg % gridDim.x, by = wg / gridDim.x;
    int m0 = by * 128, n0 = bx * 128;

    // B source for this block's 128 columns (row-region uniform per block).
    const short* Bblk;
    if constexpr (ROPE == 3)
        Bblk = (n0 < 2048) ? Bm + (long)n0 * K : B2 + (long)(n0 - 2048) * K;
    else
        Bblk = Bm + (long)n0 * K;

    floatx4 acc[4][4];
    for (int i = 0; i < 4; i++)
        for (int j = 0; j < 4; j++) acc[i][j] = (floatx4){0.f, 0.f, 0.f, 0.f};

    int srow = lane >> 2;           // 0..15
    int skc  = (lane & 3) * 8;      // 0,8,16,24

    for (int k0 = 0; k0 < K; k0 += 32) {
        __syncthreads();
        for (int i = 0; i < 2; i++) {
            int r16 = wave * 32 + i * 16;
            load_lds16(A + (long)(m0 + r16 + srow) * K + k0 + skc, &As[r16 * 32]);
            load_lds16(Bblk + (long)(r16 + srow) * K + k0 + skc, &Bs[r16 * 32]);
        }
        __syncthreads();

        short8 af[4], bfr[4];
        for (int i = 0; i < 4; i++)
            af[i] = *(const short8*)&As[(wm * 64 + i * 16 + l16) * 32 + quad * 8];
        for (int j = 0; j < 4; j++)
            bfr[j] = *(const short8*)&Bs[(wn * 64 + j * 16 + l16) * 32 + quad * 8];
        for (int i = 0; i < 4; i++)
            for (int j = 0; j < 4; j++)
                acc[i][j] = __builtin_amdgcn_mfma_f32_16x16x32_bf16(
                    af[i], bfr[j], acc[i][j], 0, 0, 0);
    }

    if constexpr (ROPE == 3) {
        for (int j = 0; j < 4; j++) {
            int col = n0 + wn * 64 + j * 16 + l16;
            if (col >= 2560) {            // V: transposed store Vt[d][row]
                int cv = col - 2560;
                for (int i = 0; i < 4; i++) {
                    int row0 = m0 + wm * 64 + i * 16 + quad * 4;
                    short4 o;
                    o.x = f2bf(acc[i][j][0]);
                    o.y = f2bf(acc[i][j][1]);
                    o.z = f2bf(acc[i][j][2]);
                    o.w = f2bf(acc[i][j][3]);
                    *(short4*)&Vt[(long)cv * M + row0] = o;
                }
            } else {                      // Q or K: RoPE'd row-major store
                bool isK = col >= 2048;
                int hh = isK ? ((col - 2048) >> 6) : (col >> 6);
                int ii = (col & 63) >> 1;
                float c = cosb[hh * 32 + ii];
                float s = sinb[hh * 32 + ii];
                for (int i = 0; i < 4; i++) {
                    for (int r = 0; r < 4; r++) {
                        int row = m0 + wm * 64 + i * 16 + quad * 4 + r;
                        float v = acc[i][j][r];
                        float p = __shfl_xor(v, 1);   // pair partner
                        v = (col & 1) ? (p * s + v * c)    // o1 = t0*s + t1*c
                                      : (v * c - p * s);   // o0 = t0*c - t1*s
                        if (isK)
                            Kout[(long)row * 1024 + (col - 2048)] = f2bf(v);
                        else
                            ((short*)C)[(long)row * 2048 + col] = f2bf(v);
                    }
                }
            }
        }
    } else {
        for (int j = 0; j < 4; j++) {
            int col = n0 + wn * 64 + j * 16 + l16;
            for (int i = 0; i < 4; i++)
                for (int r = 0; r < 4; r++) {
                    int row = m0 + wm * 64 + i * 16 + quad * 4 + r;
                    float v = acc[i][j][r];
                    if constexpr (sizeof(OT) == 2)
                        C[(long)row * N + col] = f2bf(v);
                    else
                        C[(long)row * N + col] = v;
                }
        }
    }
}

// Fused causal GQA flash attention — Round-14: round-6 body (verified 137 us,
// VGPR 152, no spills) + residency-exact grid. At VGPR 152 the HW caps at
// 3 waves/SIMD = 3 blocks/CU, so the grid is exactly 768 = 3*256 blocks with
// near-uniform work: per (h,b), 6 blocks own tile-sets
//   {15,6} {14,7} {13,8} {12,9} {11,10} (23 iters) and {5..0} (21 iters).
// Single shift, no straggler tail, zero changes to the verified math.
// NO launch_bounds min-waves (round-7's forced cap caused 240 MB of spills).
__global__ __launch_bounds__(256) void attn_kernel(const short* __restrict__ xq,
                                                   const short* __restrict__ xk,
                                                   const short* __restrict__ vt,
                                                   short* __restrict__ out,
                                                   int kvstride) {
    __shared__ short pT[4][16][72];   // per-wave P tile [row][key] (+pad)

    int pb = blockIdx.x;              // 0..5: tile-set id (see header comment)
    int h = blockIdx.y, b = blockIdx.z;
    int kvh = h >> 2;                 // GQA repeat_interleave: head h <- kv h/4
    int tid = threadIdx.x, wave = tid >> 6, lane = tid & 63;
    int quad = lane >> 4, l16 = lane & 15;

    const short* kbase0 = xk + (long)b * kS * kvstride + kvh * kHD;
    // Vt layout: [kvh*64 + d][b*kS + s], row stride kM.
    const short* vbase = vt + (long)kvh * kHD * kM + (long)b * kS;

    // all-ones bf16 B-fragment: mfma(P, ones) puts row-sum(P) in every column
    short8 ones;
    for (int i = 0; i < 8; i++) ones[i] = (short)0x3F80;

    auto loadK = [&](short8 (&kf)[4][2], int kt) {
        const short* kbase = kbase0 + (long)kt * 64 * kvstride;
        for (int kb = 0; kb < 4; kb++) {
            const short* kp = kbase + (long)(kb * 16 + l16) * kvstride + quad * 8;
            kf[kb][0] = *(const short8*)kp;
            kf[kb][1] = *(const short8*)(kp + 32);
        }
    };

    auto process = [&](int qb) {
        int nt = qb + 1;
        int wr0  = qb * 64 + wave * 16;
        int qrow = wr0 + l16;
        int crow = wr0 + quad * 4;

        const short* qp = xq + (((long)b * kS + qrow) * kH + h) * kHD + quad * 8;
        short8 qf0 = *(const short8*)(qp);
        short8 qf1 = *(const short8*)(qp + 32);

        float m_run[4];
        floatx4 acc_l = (floatx4){0.f, 0.f, 0.f, 0.f};
        floatx4 acc_o[4];
        for (int r = 0; r < 4; r++) m_run[r] = kNegBig;
        for (int nb = 0; nb < 4; nb++) acc_o[nb] = (floatx4){0.f, 0.f, 0.f, 0.f};

        auto step = [&](short8 (&kf)[4][2], int kt) {
            // Scores (raw): Q(16xHD) x K^T(HDx64), 4 key-blocks.
            floatx4 accs[4];
            __builtin_amdgcn_s_setprio(1);
            for (int kb = 0; kb < 4; kb++) {
                accs[kb] = (floatx4){0.f, 0.f, 0.f, 0.f};
                accs[kb] = __builtin_amdgcn_mfma_f32_16x16x32_bf16(qf0, kf[kb][0], accs[kb], 0, 0, 0);
                accs[kb] = __builtin_amdgcn_mfma_f32_16x16x32_bf16(qf1, kf[kb][1], accs[kb], 0, 0, 0);
            }
            __builtin_amdgcn_s_setprio(0);

            // V fragments: issue NOW — softmax below covers the latency.
            // vf[nb][ks][j] = V[key=kt*64+ks*32+quad*8+j][d=nb*16+l16]
            short8 vf[4][2];
            for (int nb = 0; nb < 4; nb++) {
                const short* vp = vbase + (long)(nb * 16 + l16) * kM + kt * 64 + quad * 8;
                vf[nb][0] = *(const short8*)(vp);
                vf[nb][1] = *(const short8*)(vp + 32);
            }

            if (kt == nt - 1) {  // causal mask: only the diagonal tile
                for (int kb = 0; kb < 4; kb++)
                    for (int r = 0; r < 4; r++) {
                        int kj = kt * 64 + kb * 16 + l16;
                        if (kj > crow + r) accs[kb][r] = kNegBig;
                    }
            }

            // Online softmax with defer-max (16-lane exact max per row).
            float mx[4];
            for (int r = 0; r < 4; r++) {
                float m1 = fmaxf(fmaxf(accs[0][r], accs[1][r]),
                                 fmaxf(accs[2][r], accs[3][r]));
                for (int off = 1; off < 16; off <<= 1) m1 = fmaxf(m1, __shfl_xor(m1, off));
                mx[r] = m1;
            }
            bool small = (mx[0] - m_run[0] <= kDeferThr) && (mx[1] - m_run[1] <= kDeferThr) &&
                         (mx[2] - m_run[2] <= kDeferThr) && (mx[3] - m_run[3] <= kDeferThr);
            if (!__all(small)) {
                for (int r = 0; r < 4; r++) {
                    float mnew = fmaxf(m_run[r], mx[r]);
                    float alpha = exp2f((m_run[r] - mnew) * kC);
                    m_run[r] = mnew;
                    acc_l[r] *= alpha;
                    for (int nb = 0; nb < 4; nb++) acc_o[nb][r] *= alpha;
                }
            }

            // P = 2^(s*kC - m*kC); P <= 2^(kDeferThr*kC) ~ 147 (bf16-safe).
            for (int r = 0; r < 4; r++) {
                float mk = m_run[r] * kC;
                for (int kb = 0; kb < 4; kb++)
                    accs[kb][r] = exp2f(fmaf(accs[kb][r], kC, -mk));
            }

            // P -> LDS (C-layout to A-layout transpose, wave-private).
            for (int r = 0; r < 4; r++)
                for (int kb = 0; kb < 4; kb++)
                    pT[wave][quad * 4 + r][kb * 16 + l16] = f2bf_fast(accs[kb][r]);

            // PV + row-sum: P(16x64) x [V(64xHD) | ones]
            short8 pf0 = *(const short8*)&pT[wave][l16][quad * 8];
            short8 pf1 = *(const short8*)&pT[wave][l16][32 + quad * 8];
            __builtin_amdgcn_s_setprio(1);
            acc_l = __builtin_amdgcn_mfma_f32_16x16x32_bf16(pf0, ones, acc_l, 0, 0, 0);
            acc_l = __builtin_amdgcn_mfma_f32_16x16x32_bf16(pf1, ones, acc_l, 0, 0, 0);
            for (int nb = 0; nb < 4; nb++) {
                acc_o[nb] = __builtin_amdgcn_mfma_f32_16x16x32_bf16(pf0, vf[nb][0], acc_o[nb], 0, 0, 0);
                acc_o[nb] = __builtin_amdgcn_mfma_f32_16x16x32_bf16(pf1, vf[nb][1], acc_o[nb], 0, 0, 0);
            }
            __builtin_amdgcn_s_setprio(0);
        };

        // K register double-buffer: load t+1 BEFORE computing t.
        short8 kfA[4][2], kfB[4][2];
        loadK(kfA, 0);
        int kt = 0;
        while (true) {
            if (kt + 1 < nt) loadK(kfB, kt + 1);
            step(kfA, kt);
            if (++kt >= nt) break;
            if (kt + 1 < nt) loadK(kfA, kt + 1);
            step(kfB, kt);
            if (++kt >= nt) break;
        }

        // Epilogue: normalize and store (B,S,H,HD) bf16.
        for (int r = 0; r < 4; r++) {
            float inv = 1.0f / fmaxf(acc_l[r], 1e-20f);
            int row = crow + r;
            for (int nb = 0; nb < 4; nb++)
                out[(((long)b * kS + row) * kH + h) * kHD + nb * 16 + l16] =
                    f2bf(acc_o[nb][r] * inv);
        }
    };

    if (pb < 5) {           // pairs {15-pb, 6+pb}: 23 iters, heavy first
        process(15 - pb);
        process(6 + pb);
    } else {                // tiles {5..0}: 21 iters
        for (int qb = 5; qb >= 0; --qb) process(qb);
    }
}

extern "C" void kernel_launch(void* const* d_in, const int* in_sizes, int n_in,
                              void* d_out, int out_size, void* d_ws, size_t ws_size,
                              hipStream_t stream) {
    // setup_inputs order: x, freqs_cos, freqs_sin, mask, wq, wk, wv, wo
    const float* x  = (const float*)d_in[0];
    const float* fc = (const float*)d_in[1];
    const float* fs = (const float*)d_in[2];
    // d_in[3] = mask: structurally causal, implemented structurally.
    const float* wq = (const float*)d_in[4];
    const float* wk = (const float*)d_in[5];
    const float* wv = (const float*)d_in[6];
    const float* wo = (const float*)d_in[7];

    const int M = kM;                     // 4096
    const long MB = 1l << 20;

    // ws (peak 24 MiB):                   d_out (32 MiB):
    //   [ 0,16) xb   — dead after QKV GEMM  [ 0,16) xq bf16 (M x 2048)
    //   [16,24) wqb  — dead after QKV GEMM  [16,24) xkv bf16 (M x 1024, K in 0..511)
    //   [ 0,16) ao   (over xb)              [24,28) vt bf16 (512 x M, transposed V)
    //   [16,24) wob  (over wqb)             [28,32) wkvb bf16 (1024 x 2048: wk|wv)
    //                                        final: 32 MiB fp32 out (last GEMM)
    char* ws = (char*)d_ws;
    short* xb   = (short*)(ws);
    short* wqb  = (short*)(ws + 16 * MB);
    short* ao   = (short*)(ws);
    short* wob  = (short*)(ws + 16 * MB);
    char*  dob  = (char*)d_out;
    short* xq   = (short*)(dob);
    short* xkv  = (short*)(dob + 16 * MB);
    short* vt   = (short*)(dob + 24 * MB);
    short* wkvb = (short*)(dob + 28 * MB);

    const int nX  = M * kD;         // 8388608
    const int nWq = kD * kD;        // 4194304
    const int nWk = kKV * kHD * kD; // 1048576

    // One fused cast: x -> xb, wq -> wqb, wk -> wkvb[0,1M), wv -> wkvb[1M,2M)
    int total4 = (nX + nWq + 2 * nWk) / 4;
    cast4_f2b<<<(total4 + 255) / 256, 256, 0, stream>>>(
        x, wq, wk, wv, xb, wqb, wkvb, wkvb + nWk,
        nX / 4, nWq / 4, nWk / 4, nWk / 4);

    // Fused QKV projection (N = 3072): Q+RoPE -> xq, K+RoPE -> xkv, V^T -> vt.
    gemm_bt_lds<short, 3><<<dim3(3072 / 128, M / 128), 256, 0, stream>>>(
        xb, wqb, xq, M, 3072, kD, fc, fs, vt, wkvb, xkv);

    attn_kernel<<<dim3(6, kH, kB), 256, 0, stream>>>(
        xq, xkv, vt, ao, 1024);

    cast_f2b<<<(nWq / 4 + 255) / 256, 256, 0, stream>>>(wo, wob, nWq / 4);
    gemm_bt_lds<float, 0><<<dim3(kD / 128, M / 128), 256, 0, stream>>>(
        ao, wob, (float*)d_out, M, kD, kD, nullptr, nullptr, nullptr, nullptr, nullptr);
}

// Round 10
// 377.182 us; speedup vs baseline: 1.2664x; 1.1076x over previous
//
#include <hip/hip_runtime.h>
#include <hip/hip_bf16.h>

// Problem constants
constexpr int kB  = 4;
constexpr int kS  = 1024;
constexpr int kD  = 2048;
constexpr int kH  = 32;
constexpr int kKV = 8;
constexpr int kHD = 64;
constexpr int kM  = kB * kS;    // 4096
constexpr int kNT = kS / 64;    // 16 kv tiles

constexpr float kNegBig = -30000.0f;   // finite sentinel: no inf/overflow paths
constexpr float kC = 0.125f * 1.44269504f;  // 1/sqrt(HD) folded into exp2
constexpr float kDeferThr = 40.0f;     // defer-max raw threshold: P <= 2^(40*kC) ~ 147

typedef __attribute__((ext_vector_type(8))) short short8;   // 8 bf16 (4 VGPRs)
typedef __attribute__((ext_vector_type(4))) float floatx4;  // MFMA C/D

static __device__ __forceinline__ short f2bf(float f) {
    unsigned int u = __builtin_bit_cast(unsigned int, f);
    unsigned int lsb = (u >> 16) & 1u;
    u += 0x7fffu + lsb;                       // round-to-nearest-even
    return (short)(u >> 16);
}
// Cheap pack for P >= 0: round-half-up (bias ~2^-9 relative, harmless).
static __device__ __forceinline__ short f2bf_fast(float f) {
    unsigned int u = __builtin_bit_cast(unsigned int, f);
    return (short)((u + 0x8000u) >> 16);
}

// Async global->LDS, 16 B per lane. LDS dest is wave-uniform base + lane*16.
static __device__ __forceinline__ void load_lds16(const short* g, short* l) {
    __builtin_amdgcn_global_load_lds(
        (const __attribute__((address_space(1))) unsigned int*)g,
        (__attribute__((address_space(3))) unsigned int*)l, 16, 0, 0);
}

// fp32 -> bf16, vectorized x4. n4 = element_count/4.
__global__ void cast_f2b(const float* __restrict__ in, short* __restrict__ outp, int n4) {
    int gid = blockIdx.x * blockDim.x + threadIdx.x;
    if (gid >= n4) return;
    float4 v = ((const float4*)in)[gid];
    short4 o;
    o.x = f2bf(v.x); o.y = f2bf(v.y); o.z = f2bf(v.z); o.w = f2bf(v.w);
    ((short4*)outp)[gid] = o;
}

// Fused 4-source cast (x, wq, wk, wv) — one launch instead of four.
__global__ void cast4_f2b(const float* __restrict__ a, const float* __restrict__ b,
                          const float* __restrict__ c, const float* __restrict__ d,
                          short* __restrict__ oa, short* __restrict__ ob,
                          short* __restrict__ oc, short* __restrict__ od,
                          int na4, int nb4, int nc4, int nd4) {
    int gid = blockIdx.x * blockDim.x + threadIdx.x;
    const float* src; short* dst; int idx;
    if (gid < na4)                    { src = a; dst = oa; idx = gid; }
    else if (gid < na4 + nb4)         { src = b; dst = ob; idx = gid - na4; }
    else if (gid < na4 + nb4 + nc4)   { src = c; dst = oc; idx = gid - na4 - nb4; }
    else if (gid < na4+nb4+nc4+nd4)   { src = d; dst = od; idx = gid - na4 - nb4 - nc4; }
    else return;
    float4 v = ((const float4*)src)[idx];
    short4 o;
    o.x = f2bf(v.x); o.y = f2bf(v.y); o.z = f2bf(v.z); o.w = f2bf(v.w);
    ((short4*)dst)[idx] = o;
}

// C[M,N] = A[M,K] * B[N,K]^T, bf16 in, fp32 acc.
// m97 structure: 128x128 tile, BK=32, global_load_lds width=16 staging,
// 2-barrier K-loop, ds_read_b128 fragments. Block = 4 waves in 2x2.
// XCD-aware bijective blockIdx swizzle (T1); requires nwg % 8 == 0 (guarded).
// ROPE = 0: plain GEMM, OT out (fp32 for out-proj).
// ROPE = 3: fused QKV projection, N = 3072 columns:
//   cols [0,2048): Q + RoPE (head = col>>6)        -> C   [row*2048 + col]  bf16
//   cols [2048,2560): K + RoPE (head = (col-2048)>>6) -> Kout[row*1024 + col-2048]
//   cols [2560,3072): V, stored TRANSPOSED          -> Vt  [(col-2560)*M + row]
//   B rows < 2048 come from Bm (wq), rows >= 2048 from B2 (wk|wv); the split
//   at 2048 is a multiple of the 128-tile so each block reads one source.
// RoPE on fp32 acc: pair (2i,2i+1) is in adjacent lanes (l16 even/odd),
// exchanged with shfl_xor(v,1). Angle indexed by HEAD (reference quirk).
template <typename OT, int ROPE>
__global__ __launch_bounds__(256) void gemm_bt_lds(const short* __restrict__ A,
                                                   const short* __restrict__ Bm,
                                                   OT* __restrict__ C,
                                                   int M, int N, int K,
                                                   const float* __restrict__ cosb,
                                                   const float* __restrict__ sinb,
                                                   short* __restrict__ Vt,
                                                   const short* __restrict__ B2,
                                                   short* __restrict__ Kout) {
    __shared__ short As[128 * 32];
    __shared__ short Bs[128 * 32];

    int tid  = threadIdx.x;
    int wave = tid >> 6, lane = tid & 63;
    int quad = lane >> 4, l16 = lane & 15;
    int wm = wave >> 1, wn = wave & 1;

    // XCD swizzle (8 XCDs round-robin on default dispatch)
    int nwg  = gridDim.x * gridDim.y;
    int orig = blockIdx.y * gridDim.x + blockIdx.x;
    int wg   = orig;
    if ((nwg & 7) == 0) {
        int cpx = nwg >> 3;
        wg = (orig & 7) * cpx + (orig >> 3);
    }
    int bx = wg % gridDim.x, by = wg / gridDim.x;
    int m0 = by * 128, n0 = bx * 128;

    // B source for this block's 128 columns (row-region uniform per block).
    const short* Bblk;
    if constexpr (ROPE == 3)
        Bblk = (n0 < 2048) ? Bm + (long)n0 * K : B2 + (long)(n0 - 2048) * K;
    else
        Bblk = Bm + (long)n0 * K;

    floatx4 acc[4][4];
    for (int i = 0; i < 4; i++)
        for (int j = 0; j < 4; j++) acc[i][j] = (floatx4){0.f, 0.f, 0.f, 0.f};

    int srow = lane >> 2;           // 0..15
    int skc  = (lane & 3) * 8;      // 0,8,16,24

    for (int k0 = 0; k0 < K; k0 += 32) {
        __syncthreads();
        for (int i = 0; i < 2; i++) {
            int r16 = wave * 32 + i * 16;
            load_lds16(A + (long)(m0 + r16 + srow) * K + k0 + skc, &As[r16 * 32]);
            load_lds16(Bblk + (long)(r16 + srow) * K + k0 + skc, &Bs[r16 * 32]);
        }
        __syncthreads();

        short8 af[4], bfr[4];
        for (int i = 0; i < 4; i++)
            af[i] = *(const short8*)&As[(wm * 64 + i * 16 + l16) * 32 + quad * 8];
        for (int j = 0; j < 4; j++)
            bfr[j] = *(const short8*)&Bs[(wn * 64 + j * 16 + l16) * 32 + quad * 8];
        for (int i = 0; i < 4; i++)
            for (int j = 0; j < 4; j++)
                acc[i][j] = __builtin_amdgcn_mfma_f32_16x16x32_bf16(
                    af[i], bfr[j], acc[i][j], 0, 0, 0);
    }

    if constexpr (ROPE == 3) {
        for (int j = 0; j < 4; j++) {
            int col = n0 + wn * 64 + j * 16 + l16;
            if (col >= 2560) {            // V: transposed store Vt[d][row]
                int cv = col - 2560;
                for (int i = 0; i < 4; i++) {
                    int row0 = m0 + wm * 64 + i * 16 + quad * 4;
                    short4 o;
                    o.x = f2bf(acc[i][j][0]);
                    o.y = f2bf(acc[i][j][1]);
                    o.z = f2bf(acc[i][j][2]);
                    o.w = f2bf(acc[i][j][3]);
                    *(short4*)&Vt[(long)cv * M + row0] = o;
                }
            } else {                      // Q or K: RoPE'd row-major store
                bool isK = col >= 2048;
                int hh = isK ? ((col - 2048) >> 6) : (col >> 6);
                int ii = (col & 63) >> 1;
                float c = cosb[hh * 32 + ii];
                float s = sinb[hh * 32 + ii];
                for (int i = 0; i < 4; i++) {
                    for (int r = 0; r < 4; r++) {
                        int row = m0 + wm * 64 + i * 16 + quad * 4 + r;
                        float v = acc[i][j][r];
                        float p = __shfl_xor(v, 1);   // pair partner
                        v = (col & 1) ? (p * s + v * c)    // o1 = t0*s + t1*c
                                      : (v * c - p * s);   // o0 = t0*c - t1*s
                        if (isK)
                            Kout[(long)row * 1024 + (col - 2048)] = f2bf(v);
                        else
                            ((short*)C)[(long)row * 2048 + col] = f2bf(v);
                    }
                }
            }
        }
    } else {
        for (int j = 0; j < 4; j++) {
            int col = n0 + wn * 64 + j * 16 + l16;
            for (int i = 0; i < 4; i++)
                for (int r = 0; r < 4; r++) {
                    int row = m0 + wm * 64 + i * 16 + quad * 4 + r;
                    float v = acc[i][j][r];
                    if constexpr (sizeof(OT) == 2)
                        C[(long)row * N + col] = f2bf(v);
                    else
                        C[(long)row * N + col] = v;
                }
        }
    }
}

// Fused causal GQA flash attention — 32 q-rows per wave (amortization).
// Diagnosis (r2..r8): per-kv-iteration serial chain ~5000 cyc vs ~130 cyc of
// MFMA issue — latency-bound at any achievable residency. Fix = amortize:
// each wave owns TWO 16-row groups sharing one K/V fetch. 2x MFMA per iter at
// ~constant chain (group chains are independent -> ILP), K/V traffic halves.
// Load order per iter: V(t) FIRST, then QK, then K(t+1) prefetch — counted
// vmcnt for V leaves the K prefetch outstanding (FIFO), so K(t+1) latency is
// covered by softmax+PV+next-QK.
// Grid: (4, H, B) = 512 blocks; block 256 = 4 waves; block pb owns 128-row
// chunks {7-pb, pb} (16-18 iters per wave, uniform). Barrier-free.
__global__ __launch_bounds__(256) void attn_kernel(const short* __restrict__ xq,
                                                   const short* __restrict__ xk,
                                                   const short* __restrict__ vt,
                                                   short* __restrict__ out,
                                                   int kvstride) {
    __shared__ short pT[4][32][72];   // per-wave P tile [row][key] (+pad)

    int pb = blockIdx.x;              // 0..3: chunk pair {7-pb, pb}
    int h = blockIdx.y, b = blockIdx.z;
    int kvh = h >> 2;                 // GQA repeat_interleave: head h <- kv h/4
    int tid = threadIdx.x, wave = tid >> 6, lane = tid & 63;
    int quad = lane >> 4, l16 = lane & 15;

    const short* kbase0 = xk + (long)b * kS * kvstride + kvh * kHD;
    // Vt layout: [kvh*64 + d][b*kS + s], row stride kM.
    const short* vbase = vt + (long)kvh * kHD * kM + (long)b * kS;

    // all-ones bf16 B-fragment: mfma(P, ones) puts row-sum(P) in every column
    short8 ones;
    for (int i = 0; i < 8; i++) ones[i] = (short)0x3F80;

    auto loadK = [&](short8 (&kf)[4][2], int kt) {
        const short* kbase = kbase0 + (long)kt * 64 * kvstride;
#pragma unroll
        for (int kb = 0; kb < 4; kb++) {
            const short* kp = kbase + (long)(kb * 16 + l16) * kvstride + quad * 8;
            kf[kb][0] = *(const short8*)kp;
            kf[kb][1] = *(const short8*)(kp + 32);
        }
    };

    auto process = [&](int c) {
        int r0 = c * 128 + wave * 32;          // wave's first q-row (32 rows)
        int nt = (r0 + 31) / 64 + 1;           // kv tiles with any valid key

        // Q fragments for both 16-row groups (HD=64 -> 2 k-steps each)
        short8 qf[2][2];
#pragma unroll
        for (int g = 0; g < 2; g++) {
            const short* qp = xq + (((long)b * kS + r0 + g * 16 + l16) * kH + h) * kHD + quad * 8;
            qf[g][0] = *(const short8*)(qp);
            qf[g][1] = *(const short8*)(qp + 32);
        }

        float m_run[2][4];
        floatx4 acc_l[2];
        floatx4 acc_o[2][4];
#pragma unroll
        for (int g = 0; g < 2; g++) {
            acc_l[g] = (floatx4){0.f, 0.f, 0.f, 0.f};
            for (int r = 0; r < 4; r++) m_run[g][r] = kNegBig;
            for (int nb = 0; nb < 4; nb++) acc_o[g][nb] = (floatx4){0.f, 0.f, 0.f, 0.f};
        }

        short8 kf[4][2];
        loadK(kf, 0);

        for (int kt = 0; kt < nt; kt++) {
            // V fragments FIRST (oldest in vmcnt FIFO; softmax covers them).
            // vf[nb][ks][j] = V[key=kt*64+ks*32+quad*8+j][d=nb*16+l16]
            short8 vf[4][2];
#pragma unroll
            for (int nb = 0; nb < 4; nb++) {
                const short* vp = vbase + (long)(nb * 16 + l16) * kM + kt * 64 + quad * 8;
                vf[nb][0] = *(const short8*)(vp);
                vf[nb][1] = *(const short8*)(vp + 32);
            }

            // Scores: Q(32xHD) x K^T(HDx64) as two independent 16-row groups.
            floatx4 accs[2][4];
            __builtin_amdgcn_s_setprio(1);
#pragma unroll
            for (int g = 0; g < 2; g++)
#pragma unroll
                for (int kb = 0; kb < 4; kb++) {
                    accs[g][kb] = (floatx4){0.f, 0.f, 0.f, 0.f};
                    accs[g][kb] = __builtin_amdgcn_mfma_f32_16x16x32_bf16(qf[g][0], kf[kb][0], accs[g][kb], 0, 0, 0);
                    accs[g][kb] = __builtin_amdgcn_mfma_f32_16x16x32_bf16(qf[g][1], kf[kb][1], accs[g][kb], 0, 0, 0);
                }
            __builtin_amdgcn_s_setprio(0);

            // K(t+1) prefetch AFTER V issue: V's counted wait won't drain it.
            if (kt + 1 < nt) loadK(kf, kt + 1);

            // Causal mask per group, only on diagonal-crossing tiles.
#pragma unroll
            for (int g = 0; g < 2; g++) {
                int wr0g = r0 + g * 16;
                if (kt * 64 + 63 > wr0g) {
                    int crow = wr0g + quad * 4;
#pragma unroll
                    for (int kb = 0; kb < 4; kb++)
#pragma unroll
                        for (int r = 0; r < 4; r++) {
                            int kj = kt * 64 + kb * 16 + l16;
                            if (kj > crow + r) accs[g][kb][r] = kNegBig;
                        }
                }
            }

            // Online softmax with defer-max, per group (independent chains).
#pragma unroll
            for (int g = 0; g < 2; g++) {
                float mx[4];
#pragma unroll
                for (int r = 0; r < 4; r++) {
                    float m1 = fmaxf(fmaxf(accs[g][0][r], accs[g][1][r]),
                                     fmaxf(accs[g][2][r], accs[g][3][r]));
                    for (int off = 1; off < 16; off <<= 1) m1 = fmaxf(m1, __shfl_xor(m1, off));
                    mx[r] = m1;
                }
                bool small = (mx[0] - m_run[g][0] <= kDeferThr) && (mx[1] - m_run[g][1] <= kDeferThr) &&
                             (mx[2] - m_run[g][2] <= kDeferThr) && (mx[3] - m_run[g][3] <= kDeferThr);
                if (!__all(small)) {
#pragma unroll
                    for (int r = 0; r < 4; r++) {
                        float mnew = fmaxf(m_run[g][r], mx[r]);
                        float alpha = exp2f((m_run[g][r] - mnew) * kC);
                        m_run[g][r] = mnew;
                        acc_l[g][r] *= alpha;
                        for (int nb = 0; nb < 4; nb++) acc_o[g][nb][r] *= alpha;
                    }
                }
                // P = 2^(s*kC - m*kC); P <= 2^(kDeferThr*kC) ~ 147 (bf16-safe)
#pragma unroll
                for (int r = 0; r < 4; r++) {
                    float mk = m_run[g][r] * kC;
                    for (int kb = 0; kb < 4; kb++)
                        accs[g][kb][r] = exp2f(fmaf(accs[g][kb][r], kC, -mk));
                }
            }

            // P -> LDS (C-layout to A-layout transpose, wave-private).
#pragma unroll
            for (int g = 0; g < 2; g++)
#pragma unroll
                for (int r = 0; r < 4; r++)
#pragma unroll
                    for (int kb = 0; kb < 4; kb++)
                        pT[wave][g * 16 + quad * 4 + r][kb * 16 + l16] = f2bf_fast(accs[g][kb][r]);

            // PV + row-sum for both groups: P(16x64) x [V(64xHD) | ones]
            __builtin_amdgcn_s_setprio(1);
#pragma unroll
            for (int g = 0; g < 2; g++) {
                short8 pf0 = *(const short8*)&pT[wave][g * 16 + l16][quad * 8];
                short8 pf1 = *(const short8*)&pT[wave][g * 16 + l16][32 + quad * 8];
                acc_l[g] = __builtin_amdgcn_mfma_f32_16x16x32_bf16(pf0, ones, acc_l[g], 0, 0, 0);
                acc_l[g] = __builtin_amdgcn_mfma_f32_16x16x32_bf16(pf1, ones, acc_l[g], 0, 0, 0);
#pragma unroll
                for (int nb = 0; nb < 4; nb++) {
                    acc_o[g][nb] = __builtin_amdgcn_mfma_f32_16x16x32_bf16(pf0, vf[nb][0], acc_o[g][nb], 0, 0, 0);
                    acc_o[g][nb] = __builtin_amdgcn_mfma_f32_16x16x32_bf16(pf1, vf[nb][1], acc_o[g][nb], 0, 0, 0);
                }
            }
            __builtin_amdgcn_s_setprio(0);
        }

        // Epilogue: normalize and store (B,S,H,HD) bf16.
#pragma unroll
        for (int g = 0; g < 2; g++)
#pragma unroll
            for (int r = 0; r < 4; r++) {
                float inv = 1.0f / fmaxf(acc_l[g][r], 1e-20f);
                int row = r0 + g * 16 + quad * 4 + r;
                for (int nb = 0; nb < 4; nb++)
                    out[(((long)b * kS + row) * kH + h) * kHD + nb * 16 + l16] =
                        f2bf(acc_o[g][nb][r] * inv);
            }
    };

    process(7 - pb);    // heavy chunk first
    process(pb);
}

extern "C" void kernel_launch(void* const* d_in, const int* in_sizes, int n_in,
                              void* d_out, int out_size, void* d_ws, size_t ws_size,
                              hipStream_t stream) {
    // setup_inputs order: x, freqs_cos, freqs_sin, mask, wq, wk, wv, wo
    const float* x  = (const float*)d_in[0];
    const float* fc = (const float*)d_in[1];
    const float* fs = (const float*)d_in[2];
    // d_in[3] = mask: structurally causal, implemented structurally.
    const float* wq = (const float*)d_in[4];
    const float* wk = (const float*)d_in[5];
    const float* wv = (const float*)d_in[6];
    const float* wo = (const float*)d_in[7];

    const int M = kM;                     // 4096
    const long MB = 1l << 20;

    // ws (peak 24 MiB):                   d_out (32 MiB):
    //   [ 0,16) xb   — dead after QKV GEMM  [ 0,16) xq bf16 (M x 2048)
    //   [16,24) wqb  — dead after QKV GEMM  [16,24) xkv bf16 (M x 1024, K in 0..511)
    //   [ 0,16) ao   (over xb)              [24,28) vt bf16 (512 x M, transposed V)
    //   [16,24) wob  (over wqb)             [28,32) wkvb bf16 (1024 x 2048: wk|wv)
    //                                        final: 32 MiB fp32 out (last GEMM)
    char* ws = (char*)d_ws;
    short* xb   = (short*)(ws);
    short* wqb  = (short*)(ws + 16 * MB);
    short* ao   = (short*)(ws);
    short* wob  = (short*)(ws + 16 * MB);
    char*  dob  = (char*)d_out;
    short* xq   = (short*)(dob);
    short* xkv  = (short*)(dob + 16 * MB);
    short* vt   = (short*)(dob + 24 * MB);
    short* wkvb = (short*)(dob + 28 * MB);

    const int nX  = M * kD;         // 8388608
    const int nWq = kD * kD;        // 4194304
    const int nWk = kKV * kHD * kD; // 1048576

    // One fused cast: x -> xb, wq -> wqb, wk -> wkvb[0,1M), wv -> wkvb[1M,2M)
    int total4 = (nX + nWq + 2 * nWk) / 4;
    cast4_f2b<<<(total4 + 255) / 256, 256, 0, stream>>>(
        x, wq, wk, wv, xb, wqb, wkvb, wkvb + nWk,
        nX / 4, nWq / 4, nWk / 4, nWk / 4);

    // Fused QKV projection (N = 3072): Q+RoPE -> xq, K+RoPE -> xkv, V^T -> vt.
    gemm_bt_lds<short, 3><<<dim3(3072 / 128, M / 128), 256, 0, stream>>>(
        xb, wqb, xq, M, 3072, kD, fc, fs, vt, wkvb, xkv);

    attn_kernel<<<dim3(4, kH, kB), 256, 0, stream>>>(
        xq, xkv, vt, ao, 1024);

    cast_f2b<<<(nWq / 4 + 255) / 256, 256, 0, stream>>>(wo, wob, nWq / 4);
    gemm_bt_lds<float, 0><<<dim3(kD / 128, M / 128), 256, 0, stream>>>(
        ao, wob, (float*)d_out, M, kD, kD, nullptr, nullptr, nullptr, nullptr, nullptr);
}

// Round 11
// 343.611 us; speedup vs baseline: 1.3902x; 1.0977x over previous
//
#include <hip/hip_runtime.h>
#include <hip/hip_bf16.h>

// Problem constants
constexpr int kB  = 4;
constexpr int kS  = 1024;
constexpr int kD  = 2048;
constexpr int kH  = 32;
constexpr int kKV = 8;
constexpr int kHD = 64;
constexpr int kM  = kB * kS;    // 4096
constexpr int kNT = kS / 64;    // 16 kv tiles

constexpr float kNegBig = -30000.0f;   // finite sentinel: no inf/overflow paths
constexpr float kC = 0.125f * 1.44269504f;  // 1/sqrt(HD) folded into exp2
constexpr float kDeferThr = 40.0f;     // defer-max raw threshold: P <= 2^(40*kC) ~ 147

typedef __attribute__((ext_vector_type(8))) short short8;   // 8 bf16 (4 VGPRs)
typedef __attribute__((ext_vector_type(4))) float floatx4;  // MFMA C/D

static __device__ __forceinline__ short f2bf(float f) {
    unsigned int u = __builtin_bit_cast(unsigned int, f);
    unsigned int lsb = (u >> 16) & 1u;
    u += 0x7fffu + lsb;                       // round-to-nearest-even
    return (short)(u >> 16);
}
// Cheap pack for P >= 0: round-half-up (bias ~2^-9 relative, harmless).
static __device__ __forceinline__ short f2bf_fast(float f) {
    unsigned int u = __builtin_bit_cast(unsigned int, f);
    return (short)((u + 0x8000u) >> 16);
}

// Async global->LDS, 16 B per lane. LDS dest is wave-uniform base + lane*16.
static __device__ __forceinline__ void load_lds16(const short* g, short* l) {
    __builtin_amdgcn_global_load_lds(
        (const __attribute__((address_space(1))) unsigned int*)g,
        (__attribute__((address_space(3))) unsigned int*)l, 16, 0, 0);
}

// fp32 -> bf16, vectorized x4. n4 = element_count/4.
__global__ void cast_f2b(const float* __restrict__ in, short* __restrict__ outp, int n4) {
    int gid = blockIdx.x * blockDim.x + threadIdx.x;
    if (gid >= n4) return;
    float4 v = ((const float4*)in)[gid];
    short4 o;
    o.x = f2bf(v.x); o.y = f2bf(v.y); o.z = f2bf(v.z); o.w = f2bf(v.w);
    ((short4*)outp)[gid] = o;
}

// Fused 4-source cast (x, wq, wk, wv) — one launch instead of four.
__global__ void cast4_f2b(const float* __restrict__ a, const float* __restrict__ b,
                          const float* __restrict__ c, const float* __restrict__ d,
                          short* __restrict__ oa, short* __restrict__ ob,
                          short* __restrict__ oc, short* __restrict__ od,
                          int na4, int nb4, int nc4, int nd4) {
    int gid = blockIdx.x * blockDim.x + threadIdx.x;
    const float* src; short* dst; int idx;
    if (gid < na4)                    { src = a; dst = oa; idx = gid; }
    else if (gid < na4 + nb4)         { src = b; dst = ob; idx = gid - na4; }
    else if (gid < na4 + nb4 + nc4)   { src = c; dst = oc; idx = gid - na4 - nb4; }
    else if (gid < na4+nb4+nc4+nd4)   { src = d; dst = od; idx = gid - na4 - nb4 - nc4; }
    else return;
    float4 v = ((const float4*)src)[idx];
    short4 o;
    o.x = f2bf(v.x); o.y = f2bf(v.y); o.z = f2bf(v.z); o.w = f2bf(v.w);
    ((short4*)dst)[idx] = o;
}

// C[M,N] = A[M,K] * B[N,K]^T, bf16 in, fp32 acc.
// Round-11 GEMM: 128x128 tile, BK=64 (32 MFMAs per barrier-pair, half the
// barriers of BK=32), global_load_lds width=16 staging with T2 XOR-swizzle:
//   - LDS dest stays LINEAR (rule #21: gload_lds can't scatter);
//   - global SOURCE col pre-swizzled: col8 = ((lane&7) ^ (lane>>3)) * 8;
//   - ds_read col swizzled with the same involution: g ^ ((row&7)*8).
//   Net: fragment reads go from 8-way bank conflict (2.94x, m136) to 2-way
//   (free); lanes l16/l16+8 alias, 8 slots cover all 32 banks.
// XCD-aware bijective blockIdx swizzle (T1); requires nwg % 8 == 0 (guarded).
// ROPE = 0: plain GEMM, OT out (fp32 for out-proj).
// ROPE = 3: fused QKV projection, N = 3072 columns:
//   cols [0,2048): Q + RoPE (head = col>>6)        -> C   [row*2048 + col]  bf16
//   cols [2048,2560): K + RoPE (head = (col-2048)>>6) -> Kout[row*1024 + col-2048]
//   cols [2560,3072): V, stored TRANSPOSED          -> Vt  [(col-2560)*M + row]
//   B rows < 2048 come from Bm (wq), rows >= 2048 from B2 (wk|wv).
// RoPE on fp32 acc: pair (2i,2i+1) is in adjacent lanes (l16 even/odd),
// exchanged with shfl_xor(v,1). Angle indexed by HEAD (reference quirk).
template <typename OT, int ROPE>
__global__ __launch_bounds__(256) void gemm_bt_lds(const short* __restrict__ A,
                                                   const short* __restrict__ Bm,
                                                   OT* __restrict__ C,
                                                   int M, int N, int K,
                                                   const float* __restrict__ cosb,
                                                   const float* __restrict__ sinb,
                                                   short* __restrict__ Vt,
                                                   const short* __restrict__ B2,
                                                   short* __restrict__ Kout) {
    __shared__ short As[128 * 64];
    __shared__ short Bs[128 * 64];

    int tid  = threadIdx.x;
    int wave = tid >> 6, lane = tid & 63;
    int quad = lane >> 4, l16 = lane & 15;
    int wm = wave >> 1, wn = wave & 1;

    // XCD swizzle (8 XCDs round-robin on default dispatch)
    int nwg  = gridDim.x * gridDim.y;
    int orig = blockIdx.y * gridDim.x + blockIdx.x;
    int wg   = orig;
    if ((nwg & 7) == 0) {
        int cpx = nwg >> 3;
        wg = (orig & 7) * cpx + (orig >> 3);
    }
    int bx = wg % gridDim.x, by = wg / gridDim.x;
    int m0 = by * 128, n0 = bx * 128;

    // B source for this block's 128 columns (row-region uniform per block).
    const short* Bblk;
    if constexpr (ROPE == 3)
        Bblk = (n0 < 2048) ? Bm + (long)n0 * K : B2 + (long)(n0 - 2048) * K;
    else
        Bblk = Bm + (long)n0 * K;

    floatx4 acc[4][4];
    for (int i = 0; i < 4; i++)
        for (int j = 0; j < 4; j++) acc[i][j] = (floatx4){0.f, 0.f, 0.f, 0.f};

    // Staging map (BK=64): per call a wave writes 8 rows x 128 B linearly.
    // srow8 = lane>>3 (row in group), source col pre-swizzled so that the
    // LINEAR LDS image holds the swizzled layout.
    int srow8 = lane >> 3;                       // 0..7
    int scol  = (((lane & 7) ^ srow8) << 3);     // 8-short units, XOR swizzle
    int rsw   = (l16 & 7) << 3;                  // read-side XOR (same involution)

    for (int k0 = 0; k0 < K; k0 += 64) {
        __syncthreads();
#pragma unroll
        for (int i = 0; i < 4; i++) {
            int r8 = wave * 32 + i * 8;
            load_lds16(A + (long)(m0 + r8 + srow8) * K + k0 + scol, &As[r8 * 64]);
            load_lds16(Bblk + (long)(r8 + srow8) * K + k0 + scol, &Bs[r8 * 64]);
        }
        __syncthreads();

#pragma unroll
        for (int kk = 0; kk < 2; kk++) {
            int rcol = (kk * 32 + quad * 8) ^ rsw;
            short8 af[4], bfr[4];
#pragma unroll
            for (int i = 0; i < 4; i++)
                af[i] = *(const short8*)&As[(wm * 64 + i * 16 + l16) * 64 + rcol];
#pragma unroll
            for (int j = 0; j < 4; j++)
                bfr[j] = *(const short8*)&Bs[(wn * 64 + j * 16 + l16) * 64 + rcol];
#pragma unroll
            for (int i = 0; i < 4; i++)
#pragma unroll
                for (int j = 0; j < 4; j++)
                    acc[i][j] = __builtin_amdgcn_mfma_f32_16x16x32_bf16(
                        af[i], bfr[j], acc[i][j], 0, 0, 0);
        }
    }

    if constexpr (ROPE == 3) {
        for (int j = 0; j < 4; j++) {
            int col = n0 + wn * 64 + j * 16 + l16;
            if (col >= 2560) {            // V: transposed store Vt[d][row]
                int cv = col - 2560;
                for (int i = 0; i < 4; i++) {
                    int row0 = m0 + wm * 64 + i * 16 + quad * 4;
                    short4 o;
                    o.x = f2bf(acc[i][j][0]);
                    o.y = f2bf(acc[i][j][1]);
                    o.z = f2bf(acc[i][j][2]);
                    o.w = f2bf(acc[i][j][3]);
                    *(short4*)&Vt[(long)cv * M + row0] = o;
                }
            } else {                      // Q or K: RoPE'd row-major store
                bool isK = col >= 2048;
                int hh = isK ? ((col - 2048) >> 6) : (col >> 6);
                int ii = (col & 63) >> 1;
                float c = cosb[hh * 32 + ii];
                float s = sinb[hh * 32 + ii];
                for (int i = 0; i < 4; i++) {
                    for (int r = 0; r < 4; r++) {
                        int row = m0 + wm * 64 + i * 16 + quad * 4 + r;
                        float v = acc[i][j][r];
                        float p = __shfl_xor(v, 1);   // pair partner
                        v = (col & 1) ? (p * s + v * c)    // o1 = t0*s + t1*c
                                      : (v * c - p * s);   // o0 = t0*c - t1*s
                        if (isK)
                            Kout[(long)row * 1024 + (col - 2048)] = f2bf(v);
                        else
                            ((short*)C)[(long)row * 2048 + col] = f2bf(v);
                    }
                }
            }
        }
    } else {
        for (int j = 0; j < 4; j++) {
            int col = n0 + wn * 64 + j * 16 + l16;
            for (int i = 0; i < 4; i++)
                for (int r = 0; r < 4; r++) {
                    int row = m0 + wm * 64 + i * 16 + quad * 4 + r;
                    float v = acc[i][j][r];
                    if constexpr (sizeof(OT) == 2)
                        C[(long)row * N + col] = f2bf(v);
                    else
                        C[(long)row * N + col] = v;
                }
        }
    }
}

// Fused causal GQA flash attention — 32 q-rows per wave (amortization,
// verified r10: attn dropped out of top-5, ~<100 us). Unchanged this round.
__global__ __launch_bounds__(256) void attn_kernel(const short* __restrict__ xq,
                                                   const short* __restrict__ xk,
                                                   const short* __restrict__ vt,
                                                   short* __restrict__ out,
                                                   int kvstride) {
    __shared__ short pT[4][32][72];   // per-wave P tile [row][key] (+pad)

    int pb = blockIdx.x;              // 0..3: chunk pair {7-pb, pb}
    int h = blockIdx.y, b = blockIdx.z;
    int kvh = h >> 2;                 // GQA repeat_interleave: head h <- kv h/4
    int tid = threadIdx.x, wave = tid >> 6, lane = tid & 63;
    int quad = lane >> 4, l16 = lane & 15;

    const short* kbase0 = xk + (long)b * kS * kvstride + kvh * kHD;
    // Vt layout: [kvh*64 + d][b*kS + s], row stride kM.
    const short* vbase = vt + (long)kvh * kHD * kM + (long)b * kS;

    // all-ones bf16 B-fragment: mfma(P, ones) puts row-sum(P) in every column
    short8 ones;
    for (int i = 0; i < 8; i++) ones[i] = (short)0x3F80;

    auto loadK = [&](short8 (&kf)[4][2], int kt) {
        const short* kbase = kbase0 + (long)kt * 64 * kvstride;
#pragma unroll
        for (int kb = 0; kb < 4; kb++) {
            const short* kp = kbase + (long)(kb * 16 + l16) * kvstride + quad * 8;
            kf[kb][0] = *(const short8*)kp;
            kf[kb][1] = *(const short8*)(kp + 32);
        }
    };

    auto process = [&](int c) {
        int r0 = c * 128 + wave * 32;          // wave's first q-row (32 rows)
        int nt = (r0 + 31) / 64 + 1;           // kv tiles with any valid key

        // Q fragments for both 16-row groups (HD=64 -> 2 k-steps each)
        short8 qf[2][2];
#pragma unroll
        for (int g = 0; g < 2; g++) {
            const short* qp = xq + (((long)b * kS + r0 + g * 16 + l16) * kH + h) * kHD + quad * 8;
            qf[g][0] = *(const short8*)(qp);
            qf[g][1] = *(const short8*)(qp + 32);
        }

        float m_run[2][4];
        floatx4 acc_l[2];
        floatx4 acc_o[2][4];
#pragma unroll
        for (int g = 0; g < 2; g++) {
            acc_l[g] = (floatx4){0.f, 0.f, 0.f, 0.f};
            for (int r = 0; r < 4; r++) m_run[g][r] = kNegBig;
            for (int nb = 0; nb < 4; nb++) acc_o[g][nb] = (floatx4){0.f, 0.f, 0.f, 0.f};
        }

        short8 kf[4][2];
        loadK(kf, 0);

        for (int kt = 0; kt < nt; kt++) {
            // V fragments FIRST (oldest in vmcnt FIFO; softmax covers them).
            // vf[nb][ks][j] = V[key=kt*64+ks*32+quad*8+j][d=nb*16+l16]
            short8 vf[4][2];
#pragma unroll
            for (int nb = 0; nb < 4; nb++) {
                const short* vp = vbase + (long)(nb * 16 + l16) * kM + kt * 64 + quad * 8;
                vf[nb][0] = *(const short8*)(vp);
                vf[nb][1] = *(const short8*)(vp + 32);
            }

            // Scores: Q(32xHD) x K^T(HDx64) as two independent 16-row groups.
            floatx4 accs[2][4];
            __builtin_amdgcn_s_setprio(1);
#pragma unroll
            for (int g = 0; g < 2; g++)
#pragma unroll
                for (int kb = 0; kb < 4; kb++) {
                    accs[g][kb] = (floatx4){0.f, 0.f, 0.f, 0.f};
                    accs[g][kb] = __builtin_amdgcn_mfma_f32_16x16x32_bf16(qf[g][0], kf[kb][0], accs[g][kb], 0, 0, 0);
                    accs[g][kb] = __builtin_amdgcn_mfma_f32_16x16x32_bf16(qf[g][1], kf[kb][1], accs[g][kb], 0, 0, 0);
                }
            __builtin_amdgcn_s_setprio(0);

            // K(t+1) prefetch AFTER V issue: V's counted wait won't drain it.
            if (kt + 1 < nt) loadK(kf, kt + 1);

            // Causal mask per group, only on diagonal-crossing tiles.
#pragma unroll
            for (int g = 0; g < 2; g++) {
                int wr0g = r0 + g * 16;
                if (kt * 64 + 63 > wr0g) {
                    int crow = wr0g + quad * 4;
#pragma unroll
                    for (int kb = 0; kb < 4; kb++)
#pragma unroll
                        for (int r = 0; r < 4; r++) {
                            int kj = kt * 64 + kb * 16 + l16;
                            if (kj > crow + r) accs[g][kb][r] = kNegBig;
                        }
                }
            }

            // Online softmax with defer-max, per group (independent chains).
#pragma unroll
            for (int g = 0; g < 2; g++) {
                float mx[4];
#pragma unroll
                for (int r = 0; r < 4; r++) {
                    float m1 = fmaxf(fmaxf(accs[g][0][r], accs[g][1][r]),
                                     fmaxf(accs[g][2][r], accs[g][3][r]));
                    for (int off = 1; off < 16; off <<= 1) m1 = fmaxf(m1, __shfl_xor(m1, off));
                    mx[r] = m1;
                }
                bool small = (mx[0] - m_run[g][0] <= kDeferThr) && (mx[1] - m_run[g][1] <= kDeferThr) &&
                             (mx[2] - m_run[g][2] <= kDeferThr) && (mx[3] - m_run[g][3] <= kDeferThr);
                if (!__all(small)) {
#pragma unroll
                    for (int r = 0; r < 4; r++) {
                        float mnew = fmaxf(m_run[g][r], mx[r]);
                        float alpha = exp2f((m_run[g][r] - mnew) * kC);
                        m_run[g][r] = mnew;
                        acc_l[g][r] *= alpha;
                        for (int nb = 0; nb < 4; nb++) acc_o[g][nb][r] *= alpha;
                    }
                }
                // P = 2^(s*kC - m*kC); P <= 2^(kDeferThr*kC) ~ 147 (bf16-safe)
#pragma unroll
                for (int r = 0; r < 4; r++) {
                    float mk = m_run[g][r] * kC;
                    for (int kb = 0; kb < 4; kb++)
                        accs[g][kb][r] = exp2f(fmaf(accs[g][kb][r], kC, -mk));
                }
            }

            // P -> LDS (C-layout to A-layout transpose, wave-private).
#pragma unroll
            for (int g = 0; g < 2; g++)
#pragma unroll
                for (int r = 0; r < 4; r++)
#pragma unroll
                    for (int kb = 0; kb < 4; kb++)
                        pT[wave][g * 16 + quad * 4 + r][kb * 16 + l16] = f2bf_fast(accs[g][kb][r]);

            // PV + row-sum for both groups: P(16x64) x [V(64xHD) | ones]
            __builtin_amdgcn_s_setprio(1);
#pragma unroll
            for (int g = 0; g < 2; g++) {
                short8 pf0 = *(const short8*)&pT[wave][g * 16 + l16][quad * 8];
                short8 pf1 = *(const short8*)&pT[wave][g * 16 + l16][32 + quad * 8];
                acc_l[g] = __builtin_amdgcn_mfma_f32_16x16x32_bf16(pf0, ones, acc_l[g], 0, 0, 0);
                acc_l[g] = __builtin_amdgcn_mfma_f32_16x16x32_bf16(pf1, ones, acc_l[g], 0, 0, 0);
#pragma unroll
                for (int nb = 0; nb < 4; nb++) {
                    acc_o[g][nb] = __builtin_amdgcn_mfma_f32_16x16x32_bf16(pf0, vf[nb][0], acc_o[g][nb], 0, 0, 0);
                    acc_o[g][nb] = __builtin_amdgcn_mfma_f32_16x16x32_bf16(pf1, vf[nb][1], acc_o[g][nb], 0, 0, 0);
                }
            }
            __builtin_amdgcn_s_setprio(0);
        }

        // Epilogue: normalize and store (B,S,H,HD) bf16.
#pragma unroll
        for (int g = 0; g < 2; g++)
#pragma unroll
            for (int r = 0; r < 4; r++) {
                float inv = 1.0f / fmaxf(acc_l[g][r], 1e-20f);
                int row = r0 + g * 16 + quad * 4 + r;
                for (int nb = 0; nb < 4; nb++)
                    out[(((long)b * kS + row) * kH + h) * kHD + nb * 16 + l16] =
                        f2bf(acc_o[g][nb][r] * inv);
            }
    };

    process(7 - pb);    // heavy chunk first
    process(pb);
}

extern "C" void kernel_launch(void* const* d_in, const int* in_sizes, int n_in,
                              void* d_out, int out_size, void* d_ws, size_t ws_size,
                              hipStream_t stream) {
    // setup_inputs order: x, freqs_cos, freqs_sin, mask, wq, wk, wv, wo
    const float* x  = (const float*)d_in[0];
    const float* fc = (const float*)d_in[1];
    const float* fs = (const float*)d_in[2];
    // d_in[3] = mask: structurally causal, implemented structurally.
    const float* wq = (const float*)d_in[4];
    const float* wk = (const float*)d_in[5];
    const float* wv = (const float*)d_in[6];
    const float* wo = (const float*)d_in[7];

    const int M = kM;                     // 4096
    const long MB = 1l << 20;

    // ws (peak 24 MiB):                   d_out (32 MiB):
    //   [ 0,16) xb   — dead after QKV GEMM  [ 0,16) xq bf16 (M x 2048)
    //   [16,24) wqb  — dead after QKV GEMM  [16,24) xkv bf16 (M x 1024, K in 0..511)
    //   [ 0,16) ao   (over xb)              [24,28) vt bf16 (512 x M, transposed V)
    //   [16,24) wob  (over wqb)             [28,32) wkvb bf16 (1024 x 2048: wk|wv)
    //                                        final: 32 MiB fp32 out (last GEMM)
    char* ws = (char*)d_ws;
    short* xb   = (short*)(ws);
    short* wqb  = (short*)(ws + 16 * MB);
    short* ao   = (short*)(ws);
    short* wob  = (short*)(ws + 16 * MB);
    char*  dob  = (char*)d_out;
    short* xq   = (short*)(dob);
    short* xkv  = (short*)(dob + 16 * MB);
    short* vt   = (short*)(dob + 24 * MB);
    short* wkvb = (short*)(dob + 28 * MB);

    const int nX  = M * kD;         // 8388608
    const int nWq = kD * kD;        // 4194304
    const int nWk = kKV * kHD * kD; // 1048576

    // One fused cast: x -> xb, wq -> wqb, wk -> wkvb[0,1M), wv -> wkvb[1M,2M)
    int total4 = (nX + nWq + 2 * nWk) / 4;
    cast4_f2b<<<(total4 + 255) / 256, 256, 0, stream>>>(
        x, wq, wk, wv, xb, wqb, wkvb, wkvb + nWk,
        nX / 4, nWq / 4, nWk / 4, nWk / 4);

    // Fused QKV projection (N = 3072): Q+RoPE -> xq, K+RoPE -> xkv, V^T -> vt.
    gemm_bt_lds<short, 3><<<dim3(3072 / 128, M / 128), 256, 0, stream>>>(
        xb, wqb, xq, M, 3072, kD, fc, fs, vt, wkvb, xkv);

    attn_kernel<<<dim3(4, kH, kB), 256, 0, stream>>>(
        xq, xkv, vt, ao, 1024);

    cast_f2b<<<(nWq / 4 + 255) / 256, 256, 0, stream>>>(wo, wob, nWq / 4);
    gemm_bt_lds<float, 0><<<dim3(kD / 128, M / 128), 256, 0, stream>>>(
        ao, wob, (float*)d_out, M, kD, kD, nullptr, nullptr, nullptr, nullptr, nullptr);
}